// Round 5
// baseline (57.217 us; speedup 1.0000x reference)
//
#include <hip/hip_runtime.h>
#include <hip/hip_bf16.h>
#include <math.h>

// One thread per POINT. Both global streams are now pure 16B/lane coalesced
// nontemporal ops:
//   - input: block's 768 floats staged as 192 float4 nt loads -> LDS,
//     then x/y/wz read from LDS (stride-3 words = 2 lanes/bank = free).
//   - output: 4 nt float4 stores per thread, consecutive lanes -> consecutive
//     float4, via the {ca,sa,t0,t1} LDS bounce (rows 2,3 are constants).
// Divides via v_rcp_f32 (abs tolerance 0.1075 >> rcp error; measured 0.0156).

#define TRANSLATION_SCALE 1.0f
#define ROTATION_SCALE    0.1f
#define EPS               1e-5f

typedef float f32x4 __attribute__((ext_vector_type(4)));

__global__ __launch_bounds__(256) void lie_se3_kernel(
    const float* __restrict__ uv, float* __restrict__ out, int n_points)
{
    __shared__ float shin[768];        // 256 points * 3 floats
    __shared__ float shv[256 * 5];     // {ca, sa, t0, t1} per point, stride 5

    const int  t     = threadIdx.x;
    const long pbase = (long)blockIdx.x * 256;
    const long total_f = 3L * n_points;

    // ---- stage input: 192 coalesced float4 nt loads -> LDS ----
    if (t < 192) {
        long fi = pbase * 3 + (long)t * 4;       // float index of this float4
        if (fi + 4 <= total_f) {
            f32x4 v = __builtin_nontemporal_load(
                reinterpret_cast<const f32x4*>(uv) + (pbase * 3 / 4) + t);
            shin[t * 4 + 0] = v.x;
            shin[t * 4 + 1] = v.y;
            shin[t * 4 + 2] = v.z;
            shin[t * 4 + 3] = v.w;
        } else {                                  // ragged tail (last block only)
            #pragma unroll
            for (int k = 0; k < 4; ++k)
                if (fi + k < total_f) shin[t * 4 + k] = uv[fi + k];
        }
    }
    __syncthreads();

    // ---- per-point math ----
    float x  = shin[3 * t + 0] * TRANSLATION_SCALE;
    float y  = shin[3 * t + 1] * TRANSLATION_SCALE;
    float wz = shin[3 * t + 2] * ROTATION_SCALE;

    float th2 = wz * wz;
    float th  = fabsf(wz);

    float s, c;
    __sincosf(th, &s, &c);

    float rth  = __builtin_amdgcn_rcpf(th  + EPS);
    float rth2 = __builtin_amdgcn_rcpf(th2 + EPS);

    float A  = s * rth;                 // sin_div
    float Bc = (1.0f - c) * rth2;       // one_minus_cos_div
    float Cc = (1.0f - A) * rth2;       // one_minus_A_div

    float ca = 1.0f - th2 * Bc;         // R00 = R11
    float sa = wz * A;                  // R10 = -R01
    float vc = 1.0f - th2 * Cc;
    float vs = wz * Bc;

    float t0 = vc * x - vs * y;
    float t1 = vs * x + vc * y;

    shv[t * 5 + 0] = ca;
    shv[t * 5 + 1] = sa;
    shv[t * 5 + 2] = t0;
    shv[t * 5 + 3] = t1;
    __syncthreads();

    // ---- coalesced output: thread t, iter it -> local float4 row it*256+t,
    //      i.e. row sel=t&3 of local point pl = it*64 + (t>>2) ----
    const long base4 = pbase * 4;
    const int  sel   = t & 3;

    #pragma unroll
    for (int it = 0; it < 4; ++it) {
        int pl = it * 64 + (t >> 2);

        float ca_ = shv[pl * 5 + 0];                 // broadcast within 4-lane group
        float sa_ = shv[pl * 5 + 1];
        float tx_ = shv[pl * 5 + 2 + (sel & 1)];     // t0 for sel0, t1 for sel1

        // rows: sel0 [ca,-sa,0,t0]  sel1 [sa,ca,0,t1]  sel2 [0,0,1,0]  sel3 [0,0,0,1]
        f32x4 o;
        o.x = (sel == 0) ?  ca_ : (sel == 1) ? sa_ : 0.0f;
        o.y = (sel == 0) ? -sa_ : (sel == 1) ? ca_ : 0.0f;
        o.z = (sel == 2) ? 1.0f : 0.0f;
        o.w = (sel <  2) ?  tx_ : (sel == 3) ? 1.0f : 0.0f;

        if (pbase + pl < n_points)
            __builtin_nontemporal_store(o, reinterpret_cast<f32x4*>(out) + base4 + it * 256 + t);
    }
}

extern "C" void kernel_launch(void* const* d_in, const int* in_sizes, int n_in,
                              void* d_out, int out_size, void* d_ws, size_t ws_size,
                              hipStream_t stream) {
    const float* uv = (const float*)d_in[0];
    float* out = (float*)d_out;

    int n_points = in_sizes[0] / 3;              // uv is [B,3]
    int grid = (n_points + 255) / 256;

    lie_se3_kernel<<<grid, 256, 0, stream>>>(uv, out, n_points);
}

// Round 6
// 49.858 us; speedup vs baseline: 1.1476x; 1.1476x over previous
//
#include <hip/hip_runtime.h>
#include <hip/hip_bf16.h>
#include <math.h>

// One thread per POINT (4x fewer waves than thread-per-row): each wave covers
// 64 points, cutting total VALU issue ~4x vs thread-per-row. The four output
// rows per point are reassembled via a tiny LDS bounce (only the 4
// non-constant values {ca, sa, t0, t1} per point; rows 2,3 are constants),
// so global stores remain one perfectly-coalesced nontemporal float4 per
// thread. Input is read with 3 direct scalar loads (stride 12B across lanes):
// all fetched bytes are consumed and L1 absorbs the redundancy — R5 showed
// that staging input via LDS costs more (serializing barrier) than it saves.
// LDS stride 5 floats -> worst-case 2-way bank aliasing (free); the 4 lanes
// sharing a point read the same address (broadcast, conflict-free).
// Divides use v_rcp_f32 (abs tolerance 0.1075 >> rcp error; measured 0.0156).

#define TRANSLATION_SCALE 1.0f
#define ROTATION_SCALE    0.1f
#define EPS               1e-5f

typedef float f32x4 __attribute__((ext_vector_type(4)));

__global__ __launch_bounds__(256) void lie_se3_kernel(
    const float* __restrict__ uv, float* __restrict__ out, int n_points)
{
    __shared__ float sh[256 * 5];

    const int t = threadIdx.x;
    const int p = blockIdx.x * 256 + t;          // this thread's point

    float x = 0.0f, y = 0.0f, wz = 0.0f;
    if (p < n_points) {
        x  = uv[3 * p + 0] * TRANSLATION_SCALE;
        y  = uv[3 * p + 1] * TRANSLATION_SCALE;
        wz = uv[3 * p + 2] * ROTATION_SCALE;
    }

    float th2 = wz * wz;
    float th  = fabsf(wz);

    float s, c;
    __sincosf(th, &s, &c);

    float rth  = __builtin_amdgcn_rcpf(th  + EPS);
    float rth2 = __builtin_amdgcn_rcpf(th2 + EPS);

    float A  = s * rth;                 // sin_div
    float Bc = (1.0f - c) * rth2;       // one_minus_cos_div
    float Cc = (1.0f - A) * rth2;       // one_minus_A_div

    float ca = 1.0f - th2 * Bc;         // R00 = R11
    float sa = wz * A;                  // R10 = -R01
    float vc = 1.0f - th2 * Cc;
    float vs = wz * Bc;

    float t0 = vc * x - vs * y;
    float t1 = vs * x + vc * y;

    sh[t * 5 + 0] = ca;
    sh[t * 5 + 1] = sa;
    sh[t * 5 + 2] = t0;
    sh[t * 5 + 3] = t1;
    __syncthreads();

    // Output: this block owns float4 rows [blockIdx*1024, +1024).
    // Thread t, iteration it -> local float4 row f4 = it*256 + t,
    // which is row sel=t&3 of local point pl = f4>>2 = it*64 + (t>>2).
    const long base4 = (long)blockIdx.x * 1024;
    const int  sel   = t & 3;

    #pragma unroll
    for (int it = 0; it < 4; ++it) {
        int pl = it * 64 + (t >> 2);

        float ca_ = sh[pl * 5 + 0];                  // broadcast within 4-lane group
        float sa_ = sh[pl * 5 + 1];
        float tx_ = sh[pl * 5 + 2 + (sel & 1)];      // t0 for sel0, t1 for sel1

        // rows: sel0 [ca,-sa,0,t0]  sel1 [sa,ca,0,t1]  sel2 [0,0,1,0]  sel3 [0,0,0,1]
        f32x4 o;
        o.x = (sel == 0) ?  ca_ : (sel == 1) ? sa_ : 0.0f;
        o.y = (sel == 0) ? -sa_ : (sel == 1) ? ca_ : 0.0f;
        o.z = (sel == 2) ? 1.0f : 0.0f;
        o.w = (sel <  2) ?  tx_ : (sel == 3) ? 1.0f : 0.0f;

        if (blockIdx.x * 256 + pl < n_points)
            __builtin_nontemporal_store(o, reinterpret_cast<f32x4*>(out) + base4 + it * 256 + t);
    }
}

extern "C" void kernel_launch(void* const* d_in, const int* in_sizes, int n_in,
                              void* d_out, int out_size, void* d_ws, size_t ws_size,
                              hipStream_t stream) {
    const float* uv = (const float*)d_in[0];
    float* out = (float*)d_out;

    int n_points = in_sizes[0] / 3;              // uv is [B,3]
    int grid = (n_points + 255) / 256;

    lie_se3_kernel<<<grid, 256, 0, stream>>>(uv, out, n_points);
}